// Round 5
// baseline (204.833 us; speedup 1.0000x reference)
//
#include <hip/hip_runtime.h>
#include <hip/hip_bf16.h>
#include <cmath>

typedef float f32x16 __attribute__((ext_vector_type(16)));
typedef __bf16 bf16x8 __attribute__((ext_vector_type(8)));
typedef __bf16 bf16x4 __attribute__((ext_vector_type(4)));

#define NE 8
#define H 1024
#define DF 2048
#define WCOLS 16384
#define NTOK 4096
#define MROWS 8192
#define NBLK 64

// Wt layout: 64 super-panels ep = e*8 + (256-col panel). Element index:
//   (ep*32 + kb)*8192 + grp*1024 + chunk*256 + row*8 + j
//   col = (ep%8)*256 + grp*32 + row ; k = kb*32 + chunk*8 + j
// Every 1KB of Wt = one wave-wide MFMA B fragment (2 chunks x 32 cols x 8 k).
// GEMM reads B fragments DIRECTLY from global (L1/L2-served, no LDS).

typedef const __attribute__((address_space(1))) unsigned int glb_u32;
typedef __attribute__((address_space(3))) unsigned int lds_u32;

__device__ __forceinline__ void async_load16(const void* g, void* l) {
    __builtin_amdgcn_global_load_lds((glb_u32*)g, (lds_u32*)l, 16, 0, 0);
}

// ---------------- kernel 1: router + x->bf16 (1024 blocks) ------------------
__global__ __launch_bounds__(256) void router_kernel(
    const float* __restrict__ x, const float* __restrict__ rw,
    float* __restrict__ logits, int* __restrict__ sel, float* __restrict__ rwn,
    __bf16* __restrict__ xb)
{
    int b = blockIdx.x;
    int tid = threadIdx.x;
    int tok  = b * 4 + (tid >> 6);
    int lane = tid & 63;
    const float* xr = x + (size_t)tok * H;
    __bf16* xbr = xb + (size_t)tok * H;
    float acc[NE];
#pragma unroll
    for (int e = 0; e < NE; ++e) acc[e] = 0.f;
#pragma unroll
    for (int it = 0; it < 4; ++it) {
        int k = (it * 64 + lane) * 4;
        float4 xv = *(const float4*)(xr + k);
        bf16x4 xc;
        xc[0] = (__bf16)xv.x; xc[1] = (__bf16)xv.y;
        xc[2] = (__bf16)xv.z; xc[3] = (__bf16)xv.w;
        *(bf16x4*)(xbr + k) = xc;
#pragma unroll
        for (int e = 0; e < NE; ++e) {
            float4 wv = *(const float4*)(rw + e * H + k);
            acc[e] += xv.x * wv.x + xv.y * wv.y + xv.z * wv.z + xv.w * wv.w;
        }
    }
#pragma unroll
    for (int e = 0; e < NE; ++e) {
        float v = acc[e];
#pragma unroll
        for (int off = 32; off > 0; off >>= 1) v += __shfl_xor(v, off, 64);
        acc[e] = v;
    }
    if (lane == 0) {
#pragma unroll
        for (int e = 0; e < NE; ++e) logits[tok * NE + e] = acc[e];
        int i1 = 0; float m1 = acc[0];
#pragma unroll
        for (int e = 1; e < NE; ++e) if (acc[e] > m1) { m1 = acc[e]; i1 = e; }
        int i2 = -1; float m2 = -INFINITY;
#pragma unroll
        for (int e = 0; e < NE; ++e) if (e != i1 && acc[e] > m2) { m2 = acc[e]; i2 = e; }
        float e2 = expf(m2 - m1);
        float inv = 1.f / (1.f + e2);
        sel[tok * 2]     = i1;  sel[tok * 2 + 1] = i2;
        rwn[tok * 2]     = inv; rwn[tok * 2 + 1] = e2 * inv;
    }
}

// ------ kernel 2: blocks [0,4096) = coalesced LDS-transpose of w1 -> Wt;
// ------           block 4096 = counting sort (runs concurrently, hidden) ----
__global__ __launch_bounds__(256) void mid_kernel(
    const float* __restrict__ w1, __bf16* __restrict__ Wt,
    const int* __restrict__ sel, const float* __restrict__ rwn,
    int* __restrict__ stok, float* __restrict__ srw, int* __restrict__ bexp)
{
    __shared__ float tile[32][132];
    __shared__ int cnt[NE][256];
    __shared__ int wtot[NE];
    __shared__ int ebase[NE + 1];
    int b = blockIdx.x;
    int t = threadIdx.x;

    if (b < 4096) {
        // coalesced float4 row reads -> LDS -> column-fragment bf16 writes
        int c  = b >> 5;                   // 128-col tile index, 0..127
        int kb = b & 31;
        int kk = t >> 3;                   // 0..31
        int cc = (t & 7) * 16;             // 0..112
        const float* src = w1 + (size_t)(kb * 32 + kk) * WCOLS + c * 128 + cc;
#pragma unroll
        for (int i = 0; i < 4; ++i) {
            float4 v = *(const float4*)(src + i * 4);
            *(float4*)&tile[kk][cc + i * 4] = v;
        }
        __syncthreads();
        int n = t >> 1, kc0 = (t & 1) * 16;
        bf16x8 o0, o1;
#pragma unroll
        for (int i = 0; i < 8; ++i) {
            o0[i] = (__bf16)tile[kc0 + i][n];       // k = kc0+i
            o1[i] = (__bf16)tile[kc0 + 8 + i][n];   // k = kc0+8+i
        }
        size_t tile_id = (size_t)(c >> 1) * 32 + kb;
        int group  = (c & 1) * 4 + (n >> 5);
        int chunk0 = kc0 >> 3;                       // 0 or 2
        __bf16* dst = Wt + tile_id * 8192 + group * 1024 + chunk0 * 256 + (n & 31) * 8;
        *(bf16x8*)dst         = o0;
        *(bf16x8*)(dst + 256) = o1;
        return;
    }

    // ---------------- sort: 256 threads, 32 items each ----------------
    int selv[32];
    int lc[NE];
#pragma unroll
    for (int e = 0; e < NE; ++e) lc[e] = 0;
    int base = t * 32;
#pragma unroll
    for (int j = 0; j < 32; ++j) { selv[j] = sel[base + j]; lc[selv[j]]++; }
#pragma unroll
    for (int e = 0; e < NE; ++e) cnt[e][t] = lc[e];
    __syncthreads();
    // scan: wave w handles experts {2w, 2w+1}; lane l owns cnt[e][4l..4l+4)
    int l = t & 63;
#pragma unroll
    for (int ee = 0; ee < 2; ++ee) {
        int e = (t >> 6) * 2 + ee;
        int s = 0, pre[4];
#pragma unroll
        for (int i = 0; i < 4; ++i) { pre[i] = s; s += cnt[e][l * 4 + i]; }
        int inc = s;
#pragma unroll
        for (int d = 1; d < 64; d <<= 1) {
            int v = __shfl_up(inc, d, 64);
            if (l >= d) inc += v;
        }
        if (l == 63) wtot[e] = inc;
        int excl = inc - s;
#pragma unroll
        for (int i = 0; i < 4; ++i) cnt[e][l * 4 + i] = excl + pre[i];
    }
    __syncthreads();
    if (t == 0) {
        int acc = 0;
        for (int e = 0; e < NE; ++e) { ebase[e] = acc; acc += wtot[e]; }
        ebase[NE] = acc;
    }
    __syncthreads();
    int off[NE];
#pragma unroll
    for (int e = 0; e < NE; ++e) off[e] = ebase[e] + cnt[e][t];
#pragma unroll
    for (int j = 0; j < 32; ++j) {
        int i = base + j;
        int e = selv[j];
        int pos = off[e]++;
        stok[pos] = i >> 1;
        srw[pos]  = rwn[i];
    }
    __syncthreads();
    if (t < NBLK) {
        int r = t * 128;
        int e = 0;
        while (e < NE - 1 && r >= ebase[e + 1]) ++e;
        bexp[t] = e;
    }
}

// ---- kernel 3: GEMM. 128x128 tile, 4 waves x (64x64), BK=16.
// ---- A: LDS (gathered), 4 buffers, counted vmcnt(3). B: DIRECT global
// ---- fragment loads (1KB contiguous/wave, L1/L2-served), double-prefetched.
__global__ __launch_bounds__(256, 4) void moe_gemm(
    const __bf16* __restrict__ xb, const __bf16* __restrict__ Wt,
    const int* __restrict__ stok, const float* __restrict__ srw,
    const int* __restrict__ bexp, float* __restrict__ out)
{
    __shared__ __align__(16) __bf16 smem[4 * 2048];   // 4 A-buffers x 4KB
    __shared__ int   tokS[128];
    __shared__ float rwS[128];

    int g = blockIdx.x;                        // 1024 blocks
    int by = (g & 7) * 8 + ((g >> 3) & 7);     // 0..63 (XCD swizzle)
    int bx = g >> 6;                           // 0..15 (128-col tiles)
    int tid = threadIdx.x;
    if (tid < 128) {
        tokS[tid] = stok[by * 128 + tid];
        rwS[tid]  = srw[by * 128 + tid];
    }
    int e = bexp[by];
    __syncthreads();                           // drains all counters too

    int lane = tid & 63;
    int wv   = tid >> 6;
    int l32  = lane & 31;
    int hi   = lane >> 5;

    // A staging: thread t -> slot (grp=t>>6, chunk=(t>>5)&1, row=t&31)
    const __bf16* aSrcT = xb + (size_t)tokS[(tid >> 6) * 32 + (tid & 31)] * H
                             + ((tid >> 5) & 1) * 8;
    __bf16* aDstT = smem + tid * 8;
    // B fragment base: grp = (bx&1)*4 + (wv>>1)*2 + tj ; chunk = (kt&1)*2 + hi
    const __bf16* bBase = Wt + (size_t)(e * 8 + (bx >> 1)) * 262144
                             + (size_t)((bx & 1) * 4 + (wv >> 1) * 2) * 1024
                             + hi * 256 + l32 * 8;

#define STAGE_A(kt_) async_load16(aSrcT + (kt_) * 16, aDstT + ((kt_) & 3) * 2048)
#define LOAD_B(dst_, kt_)                                                      \
    do {                                                                       \
        const __bf16* p_ = bBase + ((kt_) >> 1) * 8192 + ((kt_) & 1) * 512;    \
        dst_[0] = *(const bf16x8*)(p_);                                        \
        dst_[1] = *(const bf16x8*)(p_ + 1024);                                 \
    } while (0)

    int wm  = (wv & 1) * 64;
    int wn  = (wv >> 1) * 64;
    int agb = (wv & 1) * 2;                    // A group base
    int rdo = hi * 256 + l32 * 8;

    f32x16 acc[2][2];
#pragma unroll
    for (int i = 0; i < 2; ++i)
#pragma unroll
        for (int j = 0; j < 2; ++j)
#pragma unroll
            for (int r = 0; r < 16; ++r) acc[i][j][r] = 0.f;

    bf16x8 bE[2], bO[2];                       // named B prefetch sets (rule #20)

    // prologue: A tiles 0,1 staged; B(0) in flight
    STAGE_A(0);
    STAGE_A(1);
    LOAD_B(bE, 0);

    for (int kt = 0; kt < 64; kt += 2) {
        // ---------- even sub-iter (k-step kt, uses bE) ----------
        // outstanding: stageA(kt+1) + 2x loadB(kt) handled by reg-dep; keep 3
        asm volatile("s_waitcnt vmcnt(3)" ::: "memory");
        __builtin_amdgcn_s_barrier();          // publish A tile kt
        __builtin_amdgcn_sched_barrier(0);
        if (kt + 2 < 64) STAGE_A(kt + 2);      // buf (kt+2)&3: read 2 barriers ago
        LOAD_B(bO, kt + 1);
        {
            const __bf16* Ab = smem + (kt & 3) * 2048;
            bf16x8 af0 = *(const bf16x8*)&Ab[(agb + 0) * 512 + rdo];
            bf16x8 af1 = *(const bf16x8*)&Ab[(agb + 1) * 512 + rdo];
            __builtin_amdgcn_s_setprio(1);
            acc[0][0] = __builtin_amdgcn_mfma_f32_32x32x16_bf16(af0, bE[0], acc[0][0], 0, 0, 0);
            acc[0][1] = __builtin_amdgcn_mfma_f32_32x32x16_bf16(af0, bE[1], acc[0][1], 0, 0, 0);
            acc[1][0] = __builtin_amdgcn_mfma_f32_32x32x16_bf16(af1, bE[0], acc[1][0], 0, 0, 0);
            acc[1][1] = __builtin_amdgcn_mfma_f32_32x32x16_bf16(af1, bE[1], acc[1][1], 0, 0, 0);
            __builtin_amdgcn_s_setprio(0);
        }
        // ---------- odd sub-iter (k-step kt+1, uses bO) ----------
        asm volatile("s_waitcnt vmcnt(3)" ::: "memory");
        __builtin_amdgcn_s_barrier();          // publish A tile kt+1
        __builtin_amdgcn_sched_barrier(0);
        if (kt + 3 < 64) STAGE_A(kt + 3);
        if (kt + 2 < 64) LOAD_B(bE, kt + 2);
        {
            const __bf16* Ab = smem + ((kt + 1) & 3) * 2048;
            bf16x8 af0 = *(const bf16x8*)&Ab[(agb + 0) * 512 + rdo];
            bf16x8 af1 = *(const bf16x8*)&Ab[(agb + 1) * 512 + rdo];
            __builtin_amdgcn_s_setprio(1);
            acc[0][0] = __builtin_amdgcn_mfma_f32_32x32x16_bf16(af0, bO[0], acc[0][0], 0, 0, 0);
            acc[0][1] = __builtin_amdgcn_mfma_f32_32x32x16_bf16(af0, bO[1], acc[0][1], 0, 0, 0);
            acc[1][0] = __builtin_amdgcn_mfma_f32_32x32x16_bf16(af1, bO[0], acc[1][0], 0, 0, 0);
            acc[1][1] = __builtin_amdgcn_mfma_f32_32x32x16_bf16(af1, bO[1], acc[1][1], 0, 0, 0);
            __builtin_amdgcn_s_setprio(0);
        }
    }
#undef STAGE_A
#undef LOAD_B

    // epilogue: gelu (tanh form) * rw; C/D: row=(reg&3)+8*(reg>>2)+4*hi, col=l32
    int rowh = hi * 4;
#pragma unroll
    for (int ti = 0; ti < 2; ++ti)
#pragma unroll
        for (int reg = 0; reg < 16; ++reg) {
            int row = (reg & 3) + 8 * (reg >> 2) + rowh;
            int m = wm + ti * 32 + row;
            float rw = rwS[m];
            size_t ob = (size_t)(by * 128 + m) * DF + bx * 128 + wn + l32;
#pragma unroll
            for (int tj = 0; tj < 2; ++tj) {
                float val = acc[ti][tj][reg];
                float u = 0.7978845608028654f * val * (1.f + 0.044715f * val * val);
                float t = __expf(-2.f * fabsf(u));
                float th = (1.f - t) / (1.f + t);
                th = u < 0.f ? -th : th;
                out[ob + tj * 32] = 0.5f * val * (1.f + th) * rw;
            }
        }
}

extern "C" void kernel_launch(void* const* d_in, const int* in_sizes, int n_in,
                              void* d_out, int out_size, void* d_ws, size_t ws_size,
                              hipStream_t stream) {
    (void)in_sizes; (void)n_in; (void)out_size; (void)ws_size;
    const float* x        = (const float*)d_in[0];
    const float* router_w = (const float*)d_in[1];
    const float* w1       = (const float*)d_in[2];
    float* out    = (float*)d_out;
    float* logits = out + (size_t)MROWS * DF;

    char* ws    = (char*)d_ws;
    int*   sel  = (int*)(ws);
    float* rwn  = (float*)(ws + 0x8000);
    int*   stok = (int*)(ws + 0x10000);
    float* srw  = (float*)(ws + 0x18000);
    int*   bexp = (int*)(ws + 0x20000);
    __bf16* xb  = (__bf16*)(ws + (1 << 20));             // 8 MB
    __bf16* Wt  = (__bf16*)(ws + (1 << 20) + (8 << 20)); // 32 MB

    router_kernel<<<1024, 256, 0, stream>>>(x, router_w, logits, sel, rwn, xb);
    mid_kernel<<<4097, 256, 0, stream>>>(w1, Wt, sel, rwn, stok, srw, bexp);
    moe_gemm<<<1024, 256, 0, stream>>>(xb, Wt, stok, srw, bexp, out);
}